// Round 7
// baseline (31.630 us; speedup 1.0000x reference)
//
#include <hip/hip_runtime.h>

#define NB 512      // batch
#define ND 128      // dim
#define TALPHA 0.2f

// Single fused kernel. One block per anchor 'a', 512 threads = 8 waves,
// all 512 blocks co-resident (2 blocks/CU). Block 0's wave 0 performs the
// final reduction after spinning on per-block completion flags
// (decoupled-lookback idiom; one-way wait -> deadlock-free).
__global__ __launch_bounds__(512) void triplet_fused_kernel(
    const float*  __restrict__ x,       // [NB][ND]
    const int*    __restrict__ target,  // [NB]
    const float*  __restrict__ noise,   // [NB][NB][NB]
    float*        __restrict__ partial, // [NB] scratch
    unsigned int* __restrict__ flags,   // [NB] scratch, pre-zeroed via memset
    float*        __restrict__ out)     // [1]
{
    const int a    = blockIdx.x;
    const int tid  = threadIdx.x;
    const int lane = tid & 63;
    const int wv   = tid >> 6;          // 0..7

    __shared__ __align__(16) float d_row[NB];   // d[a][n]
    __shared__ __align__(16) int   tgt[NB];
    __shared__ int   plist[NB];
    __shared__ int   pcnt_w[8];
    __shared__ float wacc_s[8];

    const int t_mine = target[tid];
    const int ta     = target[a];       // broadcast load
    tgt[tid] = t_mine;

    // ---- ballot-compact positives (targets only; no d dependence) ----
    const bool m = (t_mine == ta) && (tid != a);
    const unsigned long long b = __ballot(m);
    if (lane == 0) pcnt_w[wv] = __popcll(b);
    __syncthreads();

    int base = 0, npos = 0;
    #pragma unroll
    for (int w = 0; w < 8; ++w) {
        base += (w < wv) ? pcnt_w[w] : 0;
        npos += pcnt_w[w];
    }
    if (m) {
        const unsigned long long lower = b & ((1ull << lane) - 1ull);
        plist[base + __popcll(lower)] = tid;
    }
    __syncthreads();

    // ---- prefetch this wave's first noise row (hides HBM under d-compute) ----
    float4 nv0, nv1;
    if (wv < npos) {
        const int p0 = plist[wv];
        const float* nr = noise + ((size_t)a * NB + (size_t)p0) * NB;
        nv0 = *reinterpret_cast<const float4*>(nr + 4 * lane);
        nv1 = *reinterpret_cast<const float4*>(nr + 256 + 4 * lane);
    }

    // ---- coalesced d-row compute ----
    // quad of lanes per row: c = k-quarter, rgrp = row-in-group-of-16.
    // At fixed j, lanes c=0..3 read 64B contiguous; every line consumed once.
    const int c    = lane & 3;
    const int rgrp = lane >> 2;
    const float4* xf4 = reinterpret_cast<const float4*>(x);

    float4 xa4[8];
    #pragma unroll
    for (int j = 0; j < 8; ++j) xa4[j] = xf4[(size_t)a * 32 + j * 4 + c];

    #pragma unroll
    for (int q = 0; q < 4; ++q) {
        const int row = q * 128 + wv * 16 + rgrp;
        const float4* rf4 = xf4 + (size_t)row * 32;
        float acc = 0.0f;
        #pragma unroll
        for (int j = 0; j < 8; ++j) {
            const float4 v = rf4[j * 4 + c];
            acc += xa4[j].x * v.x + xa4[j].y * v.y
                 + xa4[j].z * v.z + xa4[j].w * v.w;
        }
        acc += __shfl_xor(acc, 1);   // combine the quad's partial dots
        acc += __shfl_xor(acc, 2);
        if (c == 0) d_row[row] = 2.0f - 2.0f * acc;
    }
    __syncthreads();

    // ---- per-wave semi-hard mining; one positive per wave per iteration ----
    float wacc = 0.0f;
    const float4* d4 = reinterpret_cast<const float4*>(d_row);
    const int4*   t4 = reinterpret_cast<const int4*>(tgt);
    const float4 dd0 = d4[lane];
    const float4 dd1 = d4[64 + lane];
    const int4   tt0 = t4[lane];
    const int4   tt1 = t4[64 + lane];

    for (int idx = wv; idx < npos; idx += 8) {
        // prefetch next iteration's noise row
        float4 nx0, nx1;
        const int nidx = idx + 8;
        if (nidx < npos) {
            const int pn = plist[nidx];
            const float* nr = noise + ((size_t)a * NB + (size_t)pn) * NB;
            nx0 = *reinterpret_cast<const float4*>(nr + 4 * lane);
            nx1 = *reinterpret_cast<const float4*>(nr + 256 + 4 * lane);
        }

        const int p = plist[idx];
        const float d_ap = d_row[p];

        float bs = -1.0f;   // non-candidate sentinel (noise >= 0)
        int   bn = NB;

        // ascending-n order within lane; strict > keeps lowest n on ties
        #define EVAL(nn, dn, tn, sv)                                   \
        {                                                              \
            const float L = d_ap - (dn) + TALPHA;                      \
            if ((L > 0.0f) & (L < TALPHA) & ((tn) != ta)) {            \
                if ((sv) > bs) { bs = (sv); bn = (nn); }               \
            }                                                          \
        }
        EVAL(4*lane + 0,       dd0.x, tt0.x, nv0.x);
        EVAL(4*lane + 1,       dd0.y, tt0.y, nv0.y);
        EVAL(4*lane + 2,       dd0.z, tt0.z, nv0.z);
        EVAL(4*lane + 3,       dd0.w, tt0.w, nv0.w);
        EVAL(256 + 4*lane + 0, dd1.x, tt1.x, nv1.x);
        EVAL(256 + 4*lane + 1, dd1.y, tt1.y, nv1.y);
        EVAL(256 + 4*lane + 2, dd1.z, tt1.z, nv1.z);
        EVAL(256 + 4*lane + 3, dd1.w, tt1.w, nv1.w);
        #undef EVAL

        // butterfly argmax across 64 lanes; tie -> lower n (jnp.argmax order)
        #pragma unroll
        for (int off = 1; off < 64; off <<= 1) {
            const float os = __shfl_xor(bs, off);
            const int   on = __shfl_xor(bn, off);
            if (os > bs || (os == bs && on < bn)) { bs = os; bn = on; }
        }

        if (bs >= 0.0f) {   // has_cand
            wacc += d_ap - d_row[bn] + TALPHA;   // L in (0, ALPHA)
        }

        nv0 = nx0; nv1 = nx1;
    }

    if (lane == 0) wacc_s[wv] = wacc;
    __syncthreads();
    if (tid == 0) {
        float s = 0.0f;
        #pragma unroll
        for (int w = 0; w < 8; ++w) s += wacc_s[w];
        partial[a] = s;
        __threadfence();   // agent-scope release of partial[a]
        __hip_atomic_store(&flags[a], 1u, __ATOMIC_RELEASE,
                           __HIP_MEMORY_SCOPE_AGENT);
    }

    // ---- block 0, wave 0: final reduction (one-way wait on all flags) ----
    if (a == 0 && wv == 0) {
        // lane l owns flags[8l .. 8l+7]
        #pragma unroll
        for (int j = 0; j < 8; ++j) {
            const int f = lane * 8 + j;
            while (__hip_atomic_load(&flags[f], __ATOMIC_RELAXED,
                                     __HIP_MEMORY_SCOPE_AGENT) == 0u) {
                __builtin_amdgcn_s_sleep(2);
            }
        }
        __threadfence();   // acquire: L1 invalidate, order partial[] reads

        // identical fixed summation order to the previous reduce kernel
        float s = 0.0f;
        #pragma unroll
        for (int j = 0; j < 8; ++j) s += partial[lane + 64 * j];
        #pragma unroll
        for (int off = 1; off < 64; off <<= 1) s += __shfl_xor(s, off);
        if (lane == 0) out[0] = s;
    }
}

extern "C" void kernel_launch(void* const* d_in, const int* in_sizes, int n_in,
                              void* d_out, int out_size, void* d_ws, size_t ws_size,
                              hipStream_t stream) {
    const float* x      = (const float*)d_in[0];
    const int*   target = (const int*)d_in[1];
    const float* noise  = (const float*)d_in[2];
    float* out = (float*)d_out;

    float*        partial = (float*)d_ws;           // 512 floats
    unsigned int* flags   = (unsigned int*)(partial + NB);  // 512 uints

    hipMemsetAsync(flags, 0, NB * sizeof(unsigned int), stream);  // graph-safe
    triplet_fused_kernel<<<NB, 512, 0, stream>>>(x, target, noise,
                                                 partial, flags, out);
}

// Round 8
// 15.748 us; speedup vs baseline: 2.0085x; 2.0085x over previous
//
#include <hip/hip_runtime.h>

#define NB 512      // batch
#define ND 128      // dim
#define TALPHA 0.2f

// One block per anchor 'a'. 512 threads = 8 waves.
// Best-known structure (R3, 15.48 us): coalesced d-compute + per-wave mining
// with one-ahead noise prefetch + tiny deterministic reduce dispatch.
// Fusion attempts (atomicAdd R5, spin-wait R7) both regressed: cross-block
// coordination in one dispatch costs more than the 2nd dispatch here.
__global__ __launch_bounds__(512) void triplet_mine_kernel(
    const float* __restrict__ x,       // [NB][ND]
    const int*   __restrict__ target,  // [NB]
    const float* __restrict__ noise,   // [NB][NB][NB]
    float*       __restrict__ partial) // [NB]
{
    const int a    = blockIdx.x;
    const int tid  = threadIdx.x;
    const int lane = tid & 63;
    const int wv   = tid >> 6;          // 0..7

    __shared__ __align__(16) float d_row[NB];   // d[a][n]
    __shared__ __align__(16) int   tgt[NB];
    __shared__ int   plist[NB];
    __shared__ int   pcnt_w[8];
    __shared__ float wacc_s[8];

    const int t_mine = target[tid];
    const int ta     = target[a];       // broadcast load
    tgt[tid] = t_mine;

    // ---- ballot-compact positives (targets only; no d dependence) ----
    const bool m = (t_mine == ta) && (tid != a);
    const unsigned long long b = __ballot(m);
    if (lane == 0) pcnt_w[wv] = __popcll(b);
    __syncthreads();

    int base = 0, npos = 0;
    #pragma unroll
    for (int w = 0; w < 8; ++w) {
        base += (w < wv) ? pcnt_w[w] : 0;
        npos += pcnt_w[w];
    }
    if (m) {
        const unsigned long long lower = b & ((1ull << lane) - 1ull);
        plist[base + __popcll(lower)] = tid;
    }
    __syncthreads();

    // ---- prefetch this wave's first noise row (hides HBM under d-compute) ----
    float4 nv0, nv1;
    if (wv < npos) {
        const int p0 = plist[wv];
        const float* nr = noise + ((size_t)a * NB + (size_t)p0) * NB;
        nv0 = *reinterpret_cast<const float4*>(nr + 4 * lane);
        nv1 = *reinterpret_cast<const float4*>(nr + 256 + 4 * lane);
    }

    // ---- coalesced d-row compute ----
    // quad of lanes per row: c = k-quarter, rgrp = row-in-group-of-16.
    // At fixed j, lanes c=0..3 read 64B contiguous; every line consumed once.
    const int c    = lane & 3;
    const int rgrp = lane >> 2;
    const float4* xf4 = reinterpret_cast<const float4*>(x);

    float4 xa4[8];
    #pragma unroll
    for (int j = 0; j < 8; ++j) xa4[j] = xf4[(size_t)a * 32 + j * 4 + c];

    #pragma unroll
    for (int q = 0; q < 4; ++q) {
        const int row = q * 128 + wv * 16 + rgrp;
        const float4* rf4 = xf4 + (size_t)row * 32;
        float acc = 0.0f;
        #pragma unroll
        for (int j = 0; j < 8; ++j) {
            const float4 v = rf4[j * 4 + c];
            acc += xa4[j].x * v.x + xa4[j].y * v.y
                 + xa4[j].z * v.z + xa4[j].w * v.w;
        }
        acc += __shfl_xor(acc, 1);   // combine the quad's partial dots
        acc += __shfl_xor(acc, 2);
        if (c == 0) d_row[row] = 2.0f - 2.0f * acc;
    }
    __syncthreads();

    // ---- per-wave semi-hard mining; one positive per wave per iteration ----
    float wacc = 0.0f;
    const float4* d4 = reinterpret_cast<const float4*>(d_row);
    const int4*   t4 = reinterpret_cast<const int4*>(tgt);
    const float4 dd0 = d4[lane];
    const float4 dd1 = d4[64 + lane];
    const int4   tt0 = t4[lane];
    const int4   tt1 = t4[64 + lane];

    for (int idx = wv; idx < npos; idx += 8) {
        // prefetch next iteration's noise row
        float4 nx0, nx1;
        const int nidx = idx + 8;
        if (nidx < npos) {
            const int pn = plist[nidx];
            const float* nr = noise + ((size_t)a * NB + (size_t)pn) * NB;
            nx0 = *reinterpret_cast<const float4*>(nr + 4 * lane);
            nx1 = *reinterpret_cast<const float4*>(nr + 256 + 4 * lane);
        }

        const int p = plist[idx];
        const float d_ap = d_row[p];

        float bs = -1.0f;   // non-candidate sentinel (noise >= 0)
        int   bn = NB;

        // ascending-n order within lane; strict > keeps lowest n on ties
        #define EVAL(nn, dn, tn, sv)                                   \
        {                                                              \
            const float L = d_ap - (dn) + TALPHA;                      \
            if ((L > 0.0f) & (L < TALPHA) & ((tn) != ta)) {            \
                if ((sv) > bs) { bs = (sv); bn = (nn); }               \
            }                                                          \
        }
        EVAL(4*lane + 0,       dd0.x, tt0.x, nv0.x);
        EVAL(4*lane + 1,       dd0.y, tt0.y, nv0.y);
        EVAL(4*lane + 2,       dd0.z, tt0.z, nv0.z);
        EVAL(4*lane + 3,       dd0.w, tt0.w, nv0.w);
        EVAL(256 + 4*lane + 0, dd1.x, tt1.x, nv1.x);
        EVAL(256 + 4*lane + 1, dd1.y, tt1.y, nv1.y);
        EVAL(256 + 4*lane + 2, dd1.z, tt1.z, nv1.z);
        EVAL(256 + 4*lane + 3, dd1.w, tt1.w, nv1.w);
        #undef EVAL

        // butterfly argmax across 64 lanes; tie -> lower n (jnp.argmax order)
        #pragma unroll
        for (int off = 1; off < 64; off <<= 1) {
            const float os = __shfl_xor(bs, off);
            const int   on = __shfl_xor(bn, off);
            if (os > bs || (os == bs && on < bn)) { bs = os; bn = on; }
        }

        if (bs >= 0.0f) {   // has_cand
            wacc += d_ap - d_row[bn] + TALPHA;   // L in (0, ALPHA)
        }

        nv0 = nx0; nv1 = nx1;
    }

    if (lane == 0) wacc_s[wv] = wacc;
    __syncthreads();
    if (tid == 0) {
        float s = 0.0f;
        #pragma unroll
        for (int w = 0; w < 8; ++w) s += wacc_s[w];
        partial[a] = s;
    }
}

// deterministic single-wave reduction of 512 partials
__global__ __launch_bounds__(64) void triplet_reduce_kernel(
    const float* __restrict__ partial, float* __restrict__ out)
{
    const int lane = threadIdx.x;
    float s = 0.0f;
    #pragma unroll
    for (int j = 0; j < 8; ++j) s += partial[lane + 64 * j];
    #pragma unroll
    for (int off = 1; off < 64; off <<= 1) s += __shfl_xor(s, off);
    if (lane == 0) out[0] = s;
}

extern "C" void kernel_launch(void* const* d_in, const int* in_sizes, int n_in,
                              void* d_out, int out_size, void* d_ws, size_t ws_size,
                              hipStream_t stream) {
    const float* x      = (const float*)d_in[0];
    const int*   target = (const int*)d_in[1];
    const float* noise  = (const float*)d_in[2];
    float* out     = (float*)d_out;
    float* partial = (float*)d_ws;   // 512 floats of scratch

    triplet_mine_kernel<<<NB, 512, 0, stream>>>(x, target, noise, partial);
    triplet_reduce_kernel<<<1, 64, 0, stream>>>(partial, out);
}